// Round 11
// baseline (219.574 us; speedup 1.0000x reference)
//
#include <hip/hip_runtime.h>
#include <math.h>

#define NPART 8192
#define NBHX  64
#define EPX   300000
#define EBX   160000
#define FOUR_OVER_PI 1.27323954473516f

typedef __attribute__((ext_vector_type(8))) short bf16x8;
typedef __attribute__((ext_vector_type(4))) float f32x4;

__device__ __forceinline__ float signf(float x){ return (x>0.f)?1.f:((x<0.f)?-1.f:0.f); }
__device__ __forceinline__ unsigned short f2bf(float f){
  unsigned u = __float_as_uint(f);
  u += 0x7FFFu + ((u >> 16) & 1u);   // RNE
  return (unsigned short)(u >> 16);
}
__device__ __forceinline__ float bf2f(unsigned short h){
  return __uint_as_float(((unsigned)h) << 16);
}
__device__ __forceinline__ float bfl(unsigned u){ return __uint_as_float(u << 16); }
__device__ __forceinline__ float bfh(unsigned u){ return __uint_as_float(u & 0xffff0000u); }

// ---------------- fused edge geometry (pp + bh) + hist zero ----------------
// gew[e*8 + j] = { src*64 + corner_base , bits(w_j) }
__global__ void geom2_kernel(const float* __restrict__ pos, const float* __restrict__ bh_pos,
                             const int* __restrict__ srcP, const int* __restrict__ dstP,
                             const int* __restrict__ srcB, const int* __restrict__ dstB,
                             uint2* __restrict__ gewP, uint2* __restrict__ gewB,
                             int* __restrict__ hist) {
  int idx = blockIdx.x*256 + threadIdx.x;
  if (idx < 4096) hist[idx] = 0;
  bool isP = idx < EPX;
  int e = isP ? idx : idx - EPX;
  if (!isP && e >= EBX) return;
  const int* src = isP ? srcP : srcB;
  const int* dst = isP ? dstP : dstB;
  const float* ppos = isP ? pos : bh_pos;
  uint2* gew = isP ? gewP : gewB;
  float inv_radius = isP ? (1.f/4.5f) : (1.f/18.f);
  int s = src[e], t = dst[e];
  if (t >= NPART) { // padding edge
    uint2 z; z.x = s*64; z.y = 0;
    for (int j=0;j<8;j++) gew[(size_t)e*8+j] = z;
    return;
  }
  float x = (ppos[s*3+0] - pos[t*3+0]) * inv_radius;
  float y = (ppos[s*3+1] - pos[t*3+1]) * inv_radius;
  float z = (ppos[s*3+2] - pos[t*3+2]) * inv_radius;
  float r2 = x*x + y*y + z*z;
  float w1 = 1.f - r2;
  float win = fminf(fmaxf(w1*w1*w1, 0.f), 1.f);
  const float eps = 1e-8f;
  float nrm = sqrtf(r2);
  float xy = x*x + y*y;
  bool caps = (1.25f*z*z > xy);
  float s_caps = sqrtf(3.f*nrm/(nrm + fabsf(z) + eps));
  float s_side = nrm / sqrtf(xy + eps);
  float sc = caps ? s_caps : s_side;
  bool valid = r2 > eps;
  float cx = valid ? x*sc : 0.f;
  float cy = valid ? y*sc : 0.f;
  float cz = valid ? (caps ? signf(z)*nrm : 1.5f*z) : 0.f;
  float rxy = sqrtf(cx*cx + cy*cy);
  bool regA = (cx*cx >= cy*cy);
  float safe_cx = (fabsf(cx) > eps) ? cx : 1.0f;
  float safe_cy = (fabsf(cy) > eps) ? cy : 1.0f;
  float uA = signf(cx)*rxy;
  float vA = uA * FOUR_OVER_PI * atanf(cy/safe_cx);
  float vB = signf(cy)*rxy;
  float uB = vB * FOUR_OVER_PI * atanf(cx/safe_cy);
  bool okxy = rxy > eps;
  float u = okxy ? (regA ? uA : uB) : 0.f;
  float v = okxy ? (regA ? vA : vB) : 0.f;
  float tt[3] = { (u+1.f)*1.5f, (v+1.f)*1.5f, (cz+1.f)*1.5f };
  int i0[3]; float f[3];
#pragma unroll
  for (int ax=0; ax<3; ax++) {
    float tf = floorf(tt[ax]);
    tf = fminf(fmaxf(tf, 0.f), 2.f);
    i0[ax] = (int)tf;
    f[ax] = tt[ax] - tf;
  }
  unsigned sb = s*64 + ((i0[0]*4 + i0[1])*4 + i0[2]);
#pragma unroll
  for (int j=0;j<8;j++) {
    float wx = (j&4) ? f[0] : 1.f - f[0];
    float wy = (j&2) ? f[1] : 1.f - f[1];
    float wz = (j&1) ? f[2] : 1.f - f[2];
    uint2 o; o.x = sb; o.y = __float_as_uint(win * wx * wy * wz);
    gew[(size_t)e*8+j] = o;
  }
}

// ---------------- fused feats + CSR for both lists ----------------
__global__ void prep_kernel(const float* __restrict__ vel, const float* __restrict__ mass,
                            const float* __restrict__ bhvel, const float* __restrict__ bhmass,
                            float* __restrict__ feats, float* __restrict__ bhfeats,
                            const int* __restrict__ dstP, const int* __restrict__ dstB,
                            int* __restrict__ rsP, int* __restrict__ rsB) {
  int i = blockIdx.x*256 + threadIdx.x;
  if (i < NPART) {
    feats[i*4+0]=vel[i*3+0]; feats[i*4+1]=vel[i*3+1]; feats[i*4+2]=vel[i*3+2]; feats[i*4+3]=mass[i];
  }
  if (i < NBHX) {
    bhfeats[i*4+0]=bhvel[i*3+0]; bhfeats[i*4+1]=bhvel[i*3+1]; bhfeats[i*4+2]=bhvel[i*3+2]; bhfeats[i*4+3]=bhmass[i];
  }
  if (i <= NPART) {
    int lo = 0, hi = EPX;
    while (lo < hi) { int mid = (lo+hi)>>1; if (dstP[mid] < i) lo = mid+1; else hi = mid; }
    rsP[i] = lo;
  }
  int k = i - (NPART+1);
  if (k >= 0 && k <= NPART) {
    int lo = 0, hi = EBX;
    while (lo < hi) { int mid = (lo+hi)>>1; if (dstB[mid] < k) lo = mid+1; else hi = mid; }
    rsB[k] = lo;
  }
}

// ---------------- fused cellhist + weight transpose ----------------
__global__ void cellw_kernel(const float* __restrict__ pos, int* __restrict__ cell,
                             int* __restrict__ hist,
                             const float* __restrict__ W1, const float* __restrict__ W2,
                             const float* __restrict__ W3,
                             unsigned short* __restrict__ BT1, unsigned short* __restrict__ BT2,
                             unsigned short* __restrict__ BT3) {
  int b = blockIdx.x;
  if (b < 32) {
    int i = b*256 + threadIdx.x;
    const float inv = 16.0f/46.0f;
    int ix = min(15, max(0, (int)(pos[i*3+0]*inv)));
    int iy = min(15, max(0, (int)(pos[i*3+1]*inv)));
    int iz = min(15, max(0, (int)(pos[i*3+2]*inv)));
    int c = (ix*16+iy)*16+iz;
    cell[i] = c;
    atomicAdd(&hist[c], 1);
    return;
  }
  int idx = (b-32)*256 + threadIdx.x;
  const int S1 = 4096*96, S2 = 4096*64, S3 = 256*64;
  if (idx < S1) {
    int n = idx/96, c = idx - n*96; int k = n>>6, d = n&63;
    BT1[idx] = f2bf(W1[((size_t)k*96 + c)*64 + d]);
  } else if (idx < S1+S2) {
    int t = idx - S1; int n = t>>6, c = t&63; int k = n>>6, d = n&63;
    BT2[t] = f2bf(W2[((size_t)k*64 + c)*64 + d]);
  } else if (idx < S1+S2+S3) {
    int t = idx - S1 - S2; int n = t>>6, c = t&63; int k = n>>2, d = n&3;
    BT3[t] = f2bf((d < 3) ? W3[((size_t)k*64 + c)*3 + d] : 0.f);
  }
}

__global__ __launch_bounds__(256) void scan_kernel(const int* __restrict__ hist, int* __restrict__ offs) {
  __shared__ int wsum[4];
  int t = threadIdx.x;
  int base = t*16;
  int loc[16]; int s = 0;
#pragma unroll
  for (int i=0;i<16;i++){ loc[i]=s; s+=hist[base+i]; }
  int lane = t & 63, wv = t >> 6;
  int pre = s;
  for (int off=1; off<64; off<<=1) {
    int v = __shfl_up(pre, off);
    if (lane >= off) pre += v;
  }
  if (lane == 63) wsum[wv] = pre;
  __syncthreads();
  int wbase = 0;
  for (int w=0; w<wv; w++) wbase += wsum[w];
  int ex = wbase + pre - s;
#pragma unroll
  for (int i=0;i<16;i++) offs[base+i] = ex + loc[i];
}
__global__ void scatterorder_kernel(const int* __restrict__ cell, int* __restrict__ offs,
                                    int* __restrict__ order) {
  int i = blockIdx.x*256 + threadIdx.x;
  if (i >= NPART) return;
  int p = atomicAdd(&offs[cell[i]], 1);
  order[p] = i;
}

// XCD-chunked swizzle
__device__ __forceinline__ int swz_block(int bid, int nb) {
  return (bid & 7)*(nb >> 3) + (bid >> 3);
}

// ---------------- Y0 build (particles + bh) ----------------
__global__ void y0_kernel(const float* __restrict__ feats4, const float* __restrict__ bhfeats,
                          const float* __restrict__ W0a, const float* __restrict__ W0b,
                          unsigned short* __restrict__ Y0a, unsigned short* __restrict__ Y0b) {
  int idx = blockIdx.x*256 + threadIdx.x;
  if (idx >= (NPART+NBHX)*256) return;
  int oct = idx & 3, k = (idx>>2) & 63, s = idx >> 8;
  bool bh = (s >= NPART);
  int sl = bh ? s - NPART : s;
  const float* fp = (bh ? bhfeats : feats4) + (size_t)sl*4;
  const float* W0 = bh ? W0b : W0a;
  unsigned short* Y = (bh ? Y0b : Y0a) + ((size_t)sl*64 + k)*32 + oct*8;
  float4 f = *(const float4*)fp;
  const float* w = W0 + (size_t)k*128 + oct*8;
  unsigned short o[8];
#pragma unroll
  for (int i=0;i<8;i++) {
    float v = f.x*w[i] + f.y*w[32+i] + f.z*w[64+i] + f.w*w[96+i];
    o[i] = f2bf(v);
  }
  uint4 u;
  u.x = (unsigned)o[0] | ((unsigned)o[1]<<16);
  u.y = (unsigned)o[2] | ((unsigned)o[3]<<16);
  u.z = (unsigned)o[4] | ((unsigned)o[5]<<16);
  u.w = (unsigned)o[6] | ((unsigned)o[7]<<16);
  *(uint4*)Y = u;
}

// ---------------- MFMA GEMM ----------------
__global__ __launch_bounds__(256) void gemm_y_kernel(
    const unsigned short* __restrict__ A, const unsigned short* __restrict__ BT,
    int KC, int Ntot, unsigned short* __restrict__ Y) {
  const int wid  = threadIdx.x >> 6;
  const int lane = threadIdx.x & 63;
  const int r = lane & 15, g = lane >> 4;
  const int m0 = blockIdx.x*128 + wid*32;
  const int n0 = blockIdx.y*64;
  f32x4 acc[2][4];
#pragma unroll
  for (int h=0;h<2;h++)
#pragma unroll
    for (int n=0;n<4;n++) acc[h][n] = (f32x4){0.f,0.f,0.f,0.f};
  const unsigned short* A0 = A + (size_t)(m0 + r)*KC;
  const unsigned short* A1 = A + (size_t)(m0 + 16 + r)*KC;
  for (int k0 = 0; k0 < KC; k0 += 32) {
    int ko = k0 + g*8;
    bf16x8 a0 = *(const bf16x8*)(A0 + ko);
    bf16x8 a1 = *(const bf16x8*)(A1 + ko);
#pragma unroll
    for (int n=0; n<4; n++) {
      bf16x8 b = *(const bf16x8*)(BT + (size_t)(n0 + n*16 + r)*KC + ko);
      acc[0][n] = __builtin_amdgcn_mfma_f32_16x16x32_bf16(a0, b, acc[0][n], 0, 0, 0);
      acc[1][n] = __builtin_amdgcn_mfma_f32_16x16x32_bf16(a1, b, acc[1][n], 0, 0, 0);
    }
  }
#pragma unroll
  for (int h=0;h<2;h++)
#pragma unroll
    for (int n=0;n<4;n++)
#pragma unroll
      for (int j=0;j<4;j++)
        Y[(size_t)(m0 + h*16 + g*4 + j)*Ntot + n0 + n*16 + r] = f2bf(acc[h][n][j]);
}

__device__ __forceinline__ void xor_add4(f32x4& a, int mask) {
  a.x += __shfl_xor(a.x, mask);
  a.y += __shfl_xor(a.y, mask);
  a.z += __shfl_xor(a.z, mask);
  a.w += __shfl_xor(a.w, mask);
}

// ---------------- layer-0 fused gather: 2 VMEM/edge ----------------
__global__ __launch_bounds__(256) void gather_l0_kernel(
    const int* __restrict__ order,
    const int* __restrict__ rsP, const uint2* __restrict__ gewP,
    const int* __restrict__ rsB, const uint2* __restrict__ gewB,
    const unsigned short* __restrict__ Y0a, const unsigned short* __restrict__ Y0b,
    const float* __restrict__ feats4, const float* __restrict__ Wd0, const float* __restrict__ bd0,
    const float* __restrict__ b0a, const float* __restrict__ b0b,
    float* __restrict__ hf, unsigned short* __restrict__ hb) {
  const int sw = swz_block(blockIdx.x, gridDim.x);
  const int node = order[sw*4 + (threadIdx.x >> 6)];
  const int lane = threadIdx.x & 63;
  const int j = lane >> 3, cg = lane & 7;
  const int koff = ((j&4)<<2) | ((j&2)<<1) | (j&1);
  f32x4 accP = {0.f,0.f,0.f,0.f}, accB = {0.f,0.f,0.f,0.f};
  {
    int e0 = rsP[node], e1 = rsP[node+1];
    int e = e0;
    for (; e + 4 <= e1; e += 4) {
      uint2 p[4]; uint2 y[4];
#pragma unroll
      for (int i=0;i<4;i++) p[i] = gewP[(size_t)(e+i)*8 + j];
#pragma unroll
      for (int i=0;i<4;i++) y[i] = *(const uint2*)(Y0a + ((size_t)(p[i].x + koff))*32 + cg*4);
#pragma unroll
      for (int i=0;i<4;i++) {
        float w = __uint_as_float(p[i].y);
        accP.x += w*bfl(y[i].x); accP.y += w*bfh(y[i].x);
        accP.z += w*bfl(y[i].y); accP.w += w*bfh(y[i].y);
      }
    }
    for (; e < e1; e++) {
      uint2 p = gewP[(size_t)e*8 + j];
      uint2 y = *(const uint2*)(Y0a + ((size_t)(p.x + koff))*32 + cg*4);
      float w = __uint_as_float(p.y);
      accP.x += w*bfl(y.x); accP.y += w*bfh(y.x);
      accP.z += w*bfl(y.y); accP.w += w*bfh(y.y);
    }
  }
  {
    int e0 = rsB[node], e1 = rsB[node+1];
    int e = e0;
    for (; e + 4 <= e1; e += 4) {
      uint2 p[4]; uint2 y[4];
#pragma unroll
      for (int i=0;i<4;i++) p[i] = gewB[(size_t)(e+i)*8 + j];
#pragma unroll
      for (int i=0;i<4;i++) y[i] = *(const uint2*)(Y0b + ((size_t)(p[i].x + koff))*32 + cg*4);
#pragma unroll
      for (int i=0;i<4;i++) {
        float w = __uint_as_float(p[i].y);
        accB.x += w*bfl(y[i].x); accB.y += w*bfh(y[i].x);
        accB.z += w*bfl(y[i].y); accB.w += w*bfh(y[i].y);
      }
    }
    for (; e < e1; e++) {
      uint2 p = gewB[(size_t)e*8 + j];
      uint2 y = *(const uint2*)(Y0b + ((size_t)(p.x + koff))*32 + cg*4);
      float w = __uint_as_float(p.y);
      accB.x += w*bfl(y.x); accB.y += w*bfh(y.x);
      accB.z += w*bfl(y.y); accB.w += w*bfh(y.y);
    }
  }
  xor_add4(accP, 8);  xor_add4(accP, 16); xor_add4(accP, 32);
  xor_add4(accB, 8);  xor_add4(accB, 16); xor_add4(accB, 32);
  if (lane < 8) {
    float4 f = *(const float4*)(feats4 + (size_t)node*4);
    float4 ba = *(const float4*)(b0a + cg*4);
    float4 bb = *(const float4*)(b0b + cg*4);
    float4 bdv = *(const float4*)(bd0 + cg*4);
    float4 w0v = *(const float4*)(Wd0 + 0*32 + cg*4);
    float4 w1v = *(const float4*)(Wd0 + 1*32 + cg*4);
    float4 w2v = *(const float4*)(Wd0 + 2*32 + cg*4);
    float4 w3v = *(const float4*)(Wd0 + 3*32 + cg*4);
    float4 dd;
    dd.x = bdv.x + f.x*w0v.x + f.y*w1v.x + f.z*w2v.x + f.w*w3v.x;
    dd.y = bdv.y + f.x*w0v.y + f.y*w1v.y + f.z*w2v.y + f.w*w3v.y;
    dd.z = bdv.z + f.x*w0v.z + f.y*w1v.z + f.z*w2v.z + f.w*w3v.z;
    dd.w = bdv.w + f.x*w0v.w + f.y*w1v.w + f.z*w2v.w + f.w*w3v.w;
    float4 c0; c0.x = accP.x + ba.x; c0.y = accP.y + ba.y; c0.z = accP.z + ba.z; c0.w = accP.w + ba.w;
    float4 cb; cb.x = accB.x + bb.x; cb.y = accB.y + bb.y; cb.z = accB.z + bb.z; cb.w = accB.w + bb.w;
    size_t o = (size_t)node*96;
    *(float4*)(hf + o + cg*4)      = c0;
    *(float4*)(hf + o + 32 + cg*4) = cb;
    *(float4*)(hf + o + 64 + cg*4) = dd;
    ushort4 u0 = {f2bf(c0.x), f2bf(c0.y), f2bf(c0.z), f2bf(c0.w)};
    ushort4 u1 = {f2bf(cb.x), f2bf(cb.y), f2bf(cb.z), f2bf(cb.w)};
    ushort4 u2 = {f2bf(dd.x), f2bf(dd.y), f2bf(dd.z), f2bf(dd.w)};
    *(ushort4*)(hb + o + cg*4)      = u0;
    *(ushort4*)(hb + o + 32 + cg*4) = u1;
    *(ushort4*)(hb + o + 64 + cg*4) = u2;
  }
}

// ---------------- fused conv-gather + dense, d=64: 2 VMEM/edge ----------------
// 1 node/block, 2 waves (edge parity). lane = (corner j, 8-ch group cg).
// Dense branch k-split across all 128 threads; wave 1 passes partials via LDS.
template<int DCIN, bool ADDSKIP>
__global__ __launch_bounds__(128) void gather64_kernel(
    const int* __restrict__ order,
    const int* __restrict__ rs, const uint2* __restrict__ gew,
    const unsigned short* __restrict__ Y,
    const float* __restrict__ Xf, const float* __restrict__ Wd, const float* __restrict__ bd,
    const float* __restrict__ bconv, const float* __restrict__ skip,
    float* __restrict__ outf, unsigned short* __restrict__ outb) {
  const int sw = swz_block(blockIdx.x, gridDim.x);
  const int node = order[sw];
  const int wave = threadIdx.x >> 6;
  const int lane = threadIdx.x & 63;
  const int j = lane >> 3, cg = lane & 7;
  const int koff = ((j&4)<<2) | ((j&2)<<1) | (j&1);
  __shared__ __align__(16) float red[64*16];
  f32x4 accA = {0.f,0.f,0.f,0.f}, accB = {0.f,0.f,0.f,0.f};
  const int e0 = rs[node], e1 = rs[node+1];
  int e = e0 + wave;
  for (; e + 6 < e1; e += 8) {           // edges e, e+2, e+4, e+6
    uint2 p[4]; uint4 y[4];
#pragma unroll
    for (int i=0;i<4;i++) p[i] = gew[(size_t)(e + i*2)*8 + j];
#pragma unroll
    for (int i=0;i<4;i++) y[i] = *(const uint4*)(Y + ((size_t)(p[i].x + koff))*64 + cg*8);
#pragma unroll
    for (int i=0;i<4;i++) {
      float w = __uint_as_float(p[i].y);
      accA.x += w*bfl(y[i].x); accA.y += w*bfh(y[i].x);
      accA.z += w*bfl(y[i].y); accA.w += w*bfh(y[i].y);
      accB.x += w*bfl(y[i].z); accB.y += w*bfh(y[i].z);
      accB.z += w*bfl(y[i].w); accB.w += w*bfh(y[i].w);
    }
  }
  for (; e < e1; e += 2) {
    uint2 p = gew[(size_t)e*8 + j];
    uint4 y = *(const uint4*)(Y + ((size_t)(p.x + koff))*64 + cg*8);
    float w = __uint_as_float(p.y);
    accA.x += w*bfl(y.x); accA.y += w*bfh(y.x);
    accA.z += w*bfl(y.y); accA.w += w*bfh(y.y);
    accB.x += w*bfl(y.z); accB.y += w*bfh(y.z);
    accB.z += w*bfl(y.w); accB.w += w*bfh(y.w);
  }
  // dense branch: k-split across 128 threads (16 segments of DCIN/16)
  constexpr int KQ = DCIN/16;
  f32x4 ddA = {0.f,0.f,0.f,0.f}, ddB = {0.f,0.f,0.f,0.f};
  {
    const int seg = wave*8 + j;
    const float* x = Xf + (size_t)node*DCIN + seg*KQ;
#pragma unroll
    for (int kk=0; kk<KQ; kk++) {
      float xv = x[kk];
      float4 w0 = *(const float4*)(Wd + (size_t)(seg*KQ+kk)*64 + cg*8);
      float4 w1 = *(const float4*)(Wd + (size_t)(seg*KQ+kk)*64 + cg*8 + 4);
      ddA.x += xv*w0.x; ddA.y += xv*w0.y; ddA.z += xv*w0.z; ddA.w += xv*w0.w;
      ddB.x += xv*w1.x; ddB.y += xv*w1.y; ddB.z += xv*w1.z; ddB.w += xv*w1.w;
    }
  }
  if (wave == 1) {
    *(f32x4*)(red + lane*16)      = accA;
    *(f32x4*)(red + lane*16 + 4)  = accB;
    *(f32x4*)(red + lane*16 + 8)  = ddA;
    *(f32x4*)(red + lane*16 + 12) = ddB;
  }
  __syncthreads();
  if (wave == 0) {
    {
      f32x4 oA = *(const f32x4*)(red + lane*16);
      f32x4 oB = *(const f32x4*)(red + lane*16 + 4);
      f32x4 oC = *(const f32x4*)(red + lane*16 + 8);
      f32x4 oD = *(const f32x4*)(red + lane*16 + 12);
      accA.x += oA.x; accA.y += oA.y; accA.z += oA.z; accA.w += oA.w;
      accB.x += oB.x; accB.y += oB.y; accB.z += oB.z; accB.w += oB.w;
      ddA.x += oC.x; ddA.y += oC.y; ddA.z += oC.z; ddA.w += oC.w;
      ddB.x += oD.x; ddB.y += oD.y; ddB.z += oD.z; ddB.w += oD.w;
    }
    xor_add4(accA, 8); xor_add4(accA, 16); xor_add4(accA, 32);
    xor_add4(accB, 8); xor_add4(accB, 16); xor_add4(accB, 32);
    xor_add4(ddA, 8);  xor_add4(ddA, 16);  xor_add4(ddA, 32);
    xor_add4(ddB, 8);  xor_add4(ddB, 16);  xor_add4(ddB, 32);
    if (lane < 8) {   // j == 0: cg = lane, channels cg*8 .. cg*8+7
      float4 bc0 = *(const float4*)(bconv + cg*8);
      float4 bc1 = *(const float4*)(bconv + cg*8 + 4);
      float4 bd0v = *(const float4*)(bd + cg*8);
      float4 bd1v = *(const float4*)(bd + cg*8 + 4);
      float4 v0, v1;
      v0.x = fmaxf(accA.x + bc0.x, 0.f) + fmaxf(ddA.x + bd0v.x, 0.f);
      v0.y = fmaxf(accA.y + bc0.y, 0.f) + fmaxf(ddA.y + bd0v.y, 0.f);
      v0.z = fmaxf(accA.z + bc0.z, 0.f) + fmaxf(ddA.z + bd0v.z, 0.f);
      v0.w = fmaxf(accA.w + bc0.w, 0.f) + fmaxf(ddA.w + bd0v.w, 0.f);
      v1.x = fmaxf(accB.x + bc1.x, 0.f) + fmaxf(ddB.x + bd1v.x, 0.f);
      v1.y = fmaxf(accB.y + bc1.y, 0.f) + fmaxf(ddB.y + bd1v.y, 0.f);
      v1.z = fmaxf(accB.z + bc1.z, 0.f) + fmaxf(ddB.z + bd1v.z, 0.f);
      v1.w = fmaxf(accB.w + bc1.w, 0.f) + fmaxf(ddB.w + bd1v.w, 0.f);
      if (ADDSKIP) {
        float4 s0 = *(const float4*)(skip + (size_t)node*64 + cg*8);
        float4 s1 = *(const float4*)(skip + (size_t)node*64 + cg*8 + 4);
        v0.x += s0.x; v0.y += s0.y; v0.z += s0.z; v0.w += s0.w;
        v1.x += s1.x; v1.y += s1.y; v1.z += s1.z; v1.w += s1.w;
      }
      *(float4*)(outf + (size_t)node*64 + cg*8)     = v0;
      *(float4*)(outf + (size_t)node*64 + cg*8 + 4) = v1;
      ushort4 u0 = {f2bf(v0.x), f2bf(v0.y), f2bf(v0.z), f2bf(v0.w)};
      ushort4 u1 = {f2bf(v1.x), f2bf(v1.y), f2bf(v1.z), f2bf(v1.w)};
      *(ushort4*)(outb + (size_t)node*64 + cg*8)     = u0;
      *(ushort4*)(outb + (size_t)node*64 + cg*8 + 4) = u1;
    }
  }
}

// ---------------- layer-3 gather (d=3): 2 VMEM/edge ----------------
__global__ __launch_bounds__(256) void gather3_kernel(
    const int* __restrict__ order,
    const int* __restrict__ rs, const uint2* __restrict__ gew,
    const unsigned short* __restrict__ Y3,
    const float* __restrict__ h2f, const float* __restrict__ Wd3, const float* __restrict__ bd3,
    const float* __restrict__ b3, float* __restrict__ out) {
  const int sw = swz_block(blockIdx.x, gridDim.x);
  const int node = order[sw*4 + (threadIdx.x >> 6)];
  const int lane = threadIdx.x & 63;
  const int e2 = lane >> 5, j = (lane >> 2) & 7, dd = lane & 3;
  const int koff = ((j&4)<<2)|((j&2)<<1)|(j&1);
  float acc = 0.f;
  const int e0 = rs[node], e1 = rs[node+1];
  for (int e = e0; e < e1; e += 2) {
    int ee = e + e2;
    bool v = ee < e1;
    int ix = v ? ee : e;
    uint2 p = gew[(size_t)ix*8 + j];
    float w = v ? __uint_as_float(p.y) : 0.f;
    acc += w * bf2f(Y3[((size_t)(p.x + koff))*4 + dd]);
  }
  acc += __shfl_xor(acc, 4);
  acc += __shfl_xor(acc, 8);
  acc += __shfl_xor(acc, 16);
  acc += __shfl_down(acc, 32);
  if (lane < 3) {
    float d3 = bd3[lane];
    const float* x = h2f + (size_t)node*64;
#pragma unroll 8
    for (int c=0;c<64;c++) d3 += x[c]*Wd3[c*3 + lane];
    out[(size_t)node*3 + lane] = acc + b3[lane] + d3;
  }
}

extern "C" void kernel_launch(void* const* d_in, const int* in_sizes, int n_in,
                              void* d_out, int out_size, void* d_ws, size_t ws_size,
                              hipStream_t stream) {
  const float* pos    = (const float*)d_in[0];
  const float* vel    = (const float*)d_in[1];
  const float* mass   = (const float*)d_in[2];
  const float* bh_pos = (const float*)d_in[3];
  const float* bh_vel = (const float*)d_in[4];
  const float* bh_mass= (const float*)d_in[5];
  const int* pp_src   = (const int*)d_in[6];
  const int* pp_dst   = (const int*)d_in[7];
  const int* bh_src   = (const int*)d_in[8];
  const int* bh_dst   = (const int*)d_in[9];
  const float* W0a=(const float*)d_in[10]; const float* b0a=(const float*)d_in[11];
  const float* Wd0=(const float*)d_in[12]; const float* bd0=(const float*)d_in[13];
  const float* W0b=(const float*)d_in[14]; const float* b0b=(const float*)d_in[15];
  const float* W1 =(const float*)d_in[16]; const float* b1 =(const float*)d_in[17];
  const float* Wd1=(const float*)d_in[18]; const float* bd1=(const float*)d_in[19];
  const float* W2 =(const float*)d_in[20]; const float* b2 =(const float*)d_in[21];
  const float* Wd2=(const float*)d_in[22]; const float* bd2=(const float*)d_in[23];
  const float* W3 =(const float*)d_in[24]; const float* b3 =(const float*)d_in[25];
  const float* Wd3=(const float*)d_in[26]; const float* bd3=(const float*)d_in[27];
  float* out = (float*)d_out;
  char* wsb = (char*)d_ws;

  size_t off = 0;
  auto alloc = [&](size_t nbytes){ size_t o = off; off += (nbytes + 255) & ~((size_t)255); return o; };
  size_t feats_o   = alloc((size_t)NPART*4*4);
  size_t bhfeats_o = alloc((size_t)NBHX*4*4);
  size_t rs_pp_o   = alloc(8256*4);
  size_t rs_bh_o   = alloc(8256*4);
  size_t gew_pp_o  = alloc((size_t)EPX*8*8);
  size_t gew_bh_o  = alloc((size_t)EBX*8*8);
  size_t hf_o  = alloc((size_t)NPART*96*4);
  size_t hb_o  = alloc((size_t)NPART*96*2);
  size_t h1f_o = alloc((size_t)NPART*64*4);
  size_t h1b_o = alloc((size_t)NPART*64*2);
  size_t h2f_o = alloc((size_t)NPART*64*4);
  size_t h2b_o = alloc((size_t)NPART*64*2);
  size_t bt1_o = alloc((size_t)4096*96*2);
  size_t bt2_o = alloc((size_t)4096*64*2);
  size_t bt3_o = alloc((size_t)256*64*2);
  size_t y0b_o = alloc((size_t)NBHX*64*32*2);
  size_t cell_o = alloc((size_t)NPART*4);
  size_t hist_o = alloc((size_t)4096*4);
  size_t order_o= alloc((size_t)NPART*4);
  size_t y_o   = alloc((size_t)NPART*4096*2);   // shared: Y0a / Y1 / Y2 / Y3

  float* featsP = (float*)(wsb + feats_o); float* bhfeatsP = (float*)(wsb + bhfeats_o);
  int* rsPP = (int*)(wsb + rs_pp_o); int* rsBH = (int*)(wsb + rs_bh_o);
  uint2* gewP = (uint2*)(wsb + gew_pp_o);
  uint2* gewB = (uint2*)(wsb + gew_bh_o);
  float* hf  = (float*)(wsb + hf_o);  unsigned short* hb  = (unsigned short*)(wsb + hb_o);
  float* h1f = (float*)(wsb + h1f_o); unsigned short* h1b = (unsigned short*)(wsb + h1b_o);
  float* h2f = (float*)(wsb + h2f_o); unsigned short* h2b = (unsigned short*)(wsb + h2b_o);
  unsigned short* BT1 = (unsigned short*)(wsb + bt1_o);
  unsigned short* BT2 = (unsigned short*)(wsb + bt2_o);
  unsigned short* BT3 = (unsigned short*)(wsb + bt3_o);
  unsigned short* Y0b = (unsigned short*)(wsb + y0b_o);
  int* cellA = (int*)(wsb + cell_o);
  int* histA = (int*)(wsb + hist_o);
  int* orderA= (int*)(wsb + order_o);
  unsigned short* Ybuf = (unsigned short*)(wsb + y_o);

  // ---- prep (4 dispatches) ----
  geom2_kernel<<<(EPX+EBX+255)/256, 256, 0, stream>>>(pos, bh_pos, pp_src, pp_dst, bh_src, bh_dst,
                                                      gewP, gewB, histA);
  prep_kernel<<<(2*(NPART+1)+255)/256, 256, 0, stream>>>(vel, mass, bh_vel, bh_mass,
                                                         featsP, bhfeatsP, pp_dst, bh_dst, rsPP, rsBH);
  cellw_kernel<<<32 + (4096*96 + 4096*64 + 256*64 + 255)/256, 256, 0, stream>>>(
      pos, cellA, histA, W1, W2, W3, BT1, BT2, BT3);
  scan_kernel<<<1, 256, 0, stream>>>(histA, histA);
  scatterorder_kernel<<<NPART/256, 256, 0, stream>>>(cellA, histA, orderA);

  // ---- layer 0 ----
  y0_kernel<<<((NPART+NBHX)*256+255)/256, 256, 0, stream>>>(featsP, bhfeatsP, W0a, W0b, Ybuf, Y0b);
  gather_l0_kernel<<<NPART/4, 256, 0, stream>>>(orderA, rsPP, gewP, rsBH, gewB,
                                                Ybuf, Y0b, featsP, Wd0, bd0, b0a, b0b, hf, hb);
  // ---- layer 1 ----
  {
    dim3 g(NPART/128, 4096/64);
    gemm_y_kernel<<<g, 256, 0, stream>>>(hb, BT1, 96, 4096, Ybuf);
    gather64_kernel<96,false><<<NPART, 128, 0, stream>>>(orderA, rsPP, gewP, Ybuf,
        hf, Wd1, bd1, b1, nullptr, h1f, h1b);
  }
  // ---- layer 2 ----
  {
    dim3 g(NPART/128, 4096/64);
    gemm_y_kernel<<<g, 256, 0, stream>>>(h1b, BT2, 64, 4096, Ybuf);
    gather64_kernel<64,true><<<NPART, 128, 0, stream>>>(orderA, rsPP, gewP, Ybuf,
        h1f, Wd2, bd2, b2, h1f, h2f, h2b);
  }
  // ---- layer 3 ----
  {
    dim3 g(NPART/128, 256/64);
    gemm_y_kernel<<<g, 256, 0, stream>>>(h2b, BT3, 64, 256, Ybuf);
    gather3_kernel<<<NPART/4, 256, 0, stream>>>(orderA, rsPP, gewP, Ybuf,
        h2f, Wd3, bd3, b3, out);
  }
}

// Round 12
// 211.277 us; speedup vs baseline: 1.0393x; 1.0393x over previous
//
#include <hip/hip_runtime.h>
#include <math.h>

#define NPART 8192
#define NBHX  64
#define EPX   300000
#define EBX   160000
#define FOUR_OVER_PI 1.27323954473516f

typedef __attribute__((ext_vector_type(8))) short bf16x8;
typedef __attribute__((ext_vector_type(4))) float f32x4;

__device__ __forceinline__ float signf(float x){ return (x>0.f)?1.f:((x<0.f)?-1.f:0.f); }
__device__ __forceinline__ unsigned short f2bf(float f){
  unsigned u = __float_as_uint(f);
  u += 0x7FFFu + ((u >> 16) & 1u);   // RNE
  return (unsigned short)(u >> 16);
}
__device__ __forceinline__ float bf2f(unsigned short h){
  return __uint_as_float(((unsigned)h) << 16);
}
__device__ __forceinline__ float bfl(unsigned u){ return __uint_as_float(u << 16); }
__device__ __forceinline__ float bfh(unsigned u){ return __uint_as_float(u & 0xffff0000u); }
__device__ __forceinline__ float f16tof(unsigned short h){
  _Float16 v = __builtin_bit_cast(_Float16, h);
  return (float)v;
}
__device__ __forceinline__ unsigned short ftof16(float f){
  _Float16 v = (_Float16)f;
  return __builtin_bit_cast(unsigned short, v);
}
// per-corner weight from compact edge record {sb, fx|fy f16, win*(1-fz), win*fz}
__device__ __forceinline__ float corner_w(const uint4& r, int j){
  float fx = f16tof((unsigned short)(r.y & 0xffffu));
  float fy = f16tof((unsigned short)(r.y >> 16));
  float wx = (j&4) ? fx : 1.f - fx;
  float wy = (j&2) ? fy : 1.f - fy;
  float wz = __uint_as_float((j&1) ? r.w : r.z);
  return wx*wy*wz;
}

// ---------------- prep: feats + CSR + hist zero ----------------
__global__ void prep_kernel(const float* __restrict__ vel, const float* __restrict__ mass,
                            const float* __restrict__ bhvel, const float* __restrict__ bhmass,
                            float* __restrict__ feats, float* __restrict__ bhfeats,
                            const int* __restrict__ dstP, const int* __restrict__ dstB,
                            int* __restrict__ rsP, int* __restrict__ rsB,
                            int* __restrict__ hist) {
  int i = blockIdx.x*256 + threadIdx.x;
  if (i < 4096) hist[i] = 0;
  if (i < NPART) {
    feats[i*4+0]=vel[i*3+0]; feats[i*4+1]=vel[i*3+1]; feats[i*4+2]=vel[i*3+2]; feats[i*4+3]=mass[i];
  }
  if (i < NBHX) {
    bhfeats[i*4+0]=bhvel[i*3+0]; bhfeats[i*4+1]=bhvel[i*3+1]; bhfeats[i*4+2]=bhvel[i*3+2]; bhfeats[i*4+3]=bhmass[i];
  }
  if (i <= NPART) {
    int lo = 0, hi = EPX;
    while (lo < hi) { int mid = (lo+hi)>>1; if (dstP[mid] < i) lo = mid+1; else hi = mid; }
    rsP[i] = lo;
  }
  int k = i - (NPART+1);
  if (k >= 0 && k <= NPART) {
    int lo = 0, hi = EBX;
    while (lo < hi) { int mid = (lo+hi)>>1; if (dstB[mid] < k) lo = mid+1; else hi = mid; }
    rsB[k] = lo;
  }
}

// ---------------- fused cellhist + weight transpose ----------------
__global__ void cellw_kernel(const float* __restrict__ pos, int* __restrict__ cell,
                             int* __restrict__ hist,
                             const float* __restrict__ W1, const float* __restrict__ W2,
                             const float* __restrict__ W3,
                             unsigned short* __restrict__ BT1, unsigned short* __restrict__ BT2,
                             unsigned short* __restrict__ BT3) {
  int b = blockIdx.x;
  if (b < 32) {
    int i = b*256 + threadIdx.x;
    const float inv = 16.0f/46.0f;
    int ix = min(15, max(0, (int)(pos[i*3+0]*inv)));
    int iy = min(15, max(0, (int)(pos[i*3+1]*inv)));
    int iz = min(15, max(0, (int)(pos[i*3+2]*inv)));
    int c = (ix*16+iy)*16+iz;
    cell[i] = c;
    atomicAdd(&hist[c], 1);
    return;
  }
  int idx = (b-32)*256 + threadIdx.x;
  const int S1 = 4096*96, S2 = 4096*64, S3 = 256*64;
  if (idx < S1) {
    int n = idx/96, c = idx - n*96; int k = n>>6, d = n&63;
    BT1[idx] = f2bf(W1[((size_t)k*96 + c)*64 + d]);
  } else if (idx < S1+S2) {
    int t = idx - S1; int n = t>>6, c = t&63; int k = n>>6, d = n&63;
    BT2[t] = f2bf(W2[((size_t)k*64 + c)*64 + d]);
  } else if (idx < S1+S2+S3) {
    int t = idx - S1 - S2; int n = t>>6, c = t&63; int k = n>>2, d = n&3;
    BT3[t] = f2bf((d < 3) ? W3[((size_t)k*64 + c)*3 + d] : 0.f);
  }
}

__global__ __launch_bounds__(256) void scan_kernel(const int* __restrict__ hist, int* __restrict__ offs) {
  __shared__ int wsum[4];
  int t = threadIdx.x;
  int base = t*16;
  int loc[16]; int s = 0;
#pragma unroll
  for (int i=0;i<16;i++){ loc[i]=s; s+=hist[base+i]; }
  int lane = t & 63, wv = t >> 6;
  int pre = s;
  for (int off=1; off<64; off<<=1) {
    int v = __shfl_up(pre, off);
    if (lane >= off) pre += v;
  }
  if (lane == 63) wsum[wv] = pre;
  __syncthreads();
  int wbase = 0;
  for (int w=0; w<wv; w++) wbase += wsum[w];
  int ex = wbase + pre - s;
#pragma unroll
  for (int i=0;i<16;i++) offs[base+i] = ex + loc[i];
}
__global__ void scatterorder_kernel(const int* __restrict__ cell, int* __restrict__ offs,
                                    int* __restrict__ order, int* __restrict__ invp) {
  int i = blockIdx.x*256 + threadIdx.x;
  if (i >= NPART) return;
  int p = atomicAdd(&offs[cell[i]], 1);
  order[p] = i;
  invp[i] = p;
}

// XCD-chunked swizzle
__device__ __forceinline__ int swz_block(int bid, int nb) {
  return (bid & 7)*(nb >> 3) + (bid >> 3);
}

// ---------------- edge geometry (pp + bh), compact 16B records ----------------
// pp records use SORTED particle row (inv[s]); bh records use bh index directly.
__global__ void geom2_kernel(const float* __restrict__ pos, const float* __restrict__ bh_pos,
                             const int* __restrict__ srcP, const int* __restrict__ dstP,
                             const int* __restrict__ srcB, const int* __restrict__ dstB,
                             const int* __restrict__ invp,
                             uint4* __restrict__ recP, uint4* __restrict__ recB) {
  int idx = blockIdx.x*256 + threadIdx.x;
  bool isP = idx < EPX;
  int e = isP ? idx : idx - EPX;
  if (!isP && e >= EBX) return;
  const int* src = isP ? srcP : srcB;
  const int* dst = isP ? dstP : dstB;
  const float* ppos = isP ? pos : bh_pos;
  uint4* rec = isP ? recP : recB;
  float inv_radius = isP ? (1.f/4.5f) : (1.f/18.f);
  int s = src[e], t = dst[e];
  unsigned srow = isP ? (unsigned)invp[s] : (unsigned)s;
  if (t >= NPART) { // padding edge: all weights 0
    uint4 z; z.x = srow*64; z.y = 0; z.z = 0; z.w = 0;
    rec[e] = z;
    return;
  }
  float x = (ppos[s*3+0] - pos[t*3+0]) * inv_radius;
  float y = (ppos[s*3+1] - pos[t*3+1]) * inv_radius;
  float z = (ppos[s*3+2] - pos[t*3+2]) * inv_radius;
  float r2 = x*x + y*y + z*z;
  float w1 = 1.f - r2;
  float win = fminf(fmaxf(w1*w1*w1, 0.f), 1.f);
  const float eps = 1e-8f;
  float nrm = sqrtf(r2);
  float xy = x*x + y*y;
  bool caps = (1.25f*z*z > xy);
  float s_caps = sqrtf(3.f*nrm/(nrm + fabsf(z) + eps));
  float s_side = nrm / sqrtf(xy + eps);
  float sc = caps ? s_caps : s_side;
  bool valid = r2 > eps;
  float cx = valid ? x*sc : 0.f;
  float cy = valid ? y*sc : 0.f;
  float cz = valid ? (caps ? signf(z)*nrm : 1.5f*z) : 0.f;
  float rxy = sqrtf(cx*cx + cy*cy);
  bool regA = (cx*cx >= cy*cy);
  float safe_cx = (fabsf(cx) > eps) ? cx : 1.0f;
  float safe_cy = (fabsf(cy) > eps) ? cy : 1.0f;
  float uA = signf(cx)*rxy;
  float vA = uA * FOUR_OVER_PI * atanf(cy/safe_cx);
  float vB = signf(cy)*rxy;
  float uB = vB * FOUR_OVER_PI * atanf(cx/safe_cy);
  bool okxy = rxy > eps;
  float u = okxy ? (regA ? uA : uB) : 0.f;
  float v = okxy ? (regA ? vA : vB) : 0.f;
  float tt[3] = { (u+1.f)*1.5f, (v+1.f)*1.5f, (cz+1.f)*1.5f };
  int i0[3]; float f[3];
#pragma unroll
  for (int ax=0; ax<3; ax++) {
    float tf = floorf(tt[ax]);
    tf = fminf(fmaxf(tf, 0.f), 2.f);
    i0[ax] = (int)tf;
    f[ax] = tt[ax] - tf;
  }
  uint4 o;
  o.x = srow*64 + ((i0[0]*4 + i0[1])*4 + i0[2]);
  o.y = (unsigned)ftof16(f[0]) | ((unsigned)ftof16(f[1]) << 16);
  o.z = __float_as_uint(win * (1.f - f[2]));
  o.w = __float_as_uint(win * f[2]);
  rec[e] = o;
}

// ---------------- Y0 build (sorted particle rows + bh) ----------------
__global__ void y0_kernel(const int* __restrict__ order,
                          const float* __restrict__ feats4, const float* __restrict__ bhfeats,
                          const float* __restrict__ W0a, const float* __restrict__ W0b,
                          unsigned short* __restrict__ Y0a, unsigned short* __restrict__ Y0b) {
  int idx = blockIdx.x*256 + threadIdx.x;
  if (idx >= (NPART+NBHX)*256) return;
  int oct = idx & 3, k = (idx>>2) & 63, s = idx >> 8;
  bool bh = (s >= NPART);
  int sl = bh ? s - NPART : s;
  int srcn = bh ? sl : order[sl];
  const float* fp = (bh ? bhfeats : feats4) + (size_t)srcn*4;
  const float* W0 = bh ? W0b : W0a;
  unsigned short* Y = (bh ? Y0b : Y0a) + ((size_t)sl*64 + k)*32 + oct*8;
  float4 f = *(const float4*)fp;
  const float* w = W0 + (size_t)k*128 + oct*8;
  unsigned short o[8];
#pragma unroll
  for (int i=0;i<8;i++) {
    float v = f.x*w[i] + f.y*w[32+i] + f.z*w[64+i] + f.w*w[96+i];
    o[i] = f2bf(v);
  }
  uint4 u;
  u.x = (unsigned)o[0] | ((unsigned)o[1]<<16);
  u.y = (unsigned)o[2] | ((unsigned)o[3]<<16);
  u.z = (unsigned)o[4] | ((unsigned)o[5]<<16);
  u.w = (unsigned)o[6] | ((unsigned)o[7]<<16);
  *(uint4*)Y = u;
}

// ---------------- MFMA GEMM (rows in sorted layout throughout) ----------------
__global__ __launch_bounds__(256) void gemm_y_kernel(
    const unsigned short* __restrict__ A, const unsigned short* __restrict__ BT,
    int KC, int Ntot, unsigned short* __restrict__ Y) {
  const int wid  = threadIdx.x >> 6;
  const int lane = threadIdx.x & 63;
  const int r = lane & 15, g = lane >> 4;
  const int m0 = blockIdx.x*128 + wid*32;
  const int n0 = blockIdx.y*64;
  f32x4 acc[2][4];
#pragma unroll
  for (int h=0;h<2;h++)
#pragma unroll
    for (int n=0;n<4;n++) acc[h][n] = (f32x4){0.f,0.f,0.f,0.f};
  const unsigned short* A0 = A + (size_t)(m0 + r)*KC;
  const unsigned short* A1 = A + (size_t)(m0 + 16 + r)*KC;
  for (int k0 = 0; k0 < KC; k0 += 32) {
    int ko = k0 + g*8;
    bf16x8 a0 = *(const bf16x8*)(A0 + ko);
    bf16x8 a1 = *(const bf16x8*)(A1 + ko);
#pragma unroll
    for (int n=0; n<4; n++) {
      bf16x8 b = *(const bf16x8*)(BT + (size_t)(n0 + n*16 + r)*KC + ko);
      acc[0][n] = __builtin_amdgcn_mfma_f32_16x16x32_bf16(a0, b, acc[0][n], 0, 0, 0);
      acc[1][n] = __builtin_amdgcn_mfma_f32_16x16x32_bf16(a1, b, acc[1][n], 0, 0, 0);
    }
  }
#pragma unroll
  for (int h=0;h<2;h++)
#pragma unroll
    for (int n=0;n<4;n++)
#pragma unroll
      for (int j=0;j<4;j++)
        Y[(size_t)(m0 + h*16 + g*4 + j)*Ntot + n0 + n*16 + r] = f2bf(acc[h][n][j]);
}

__device__ __forceinline__ void xor_add4(f32x4& a, int mask) {
  a.x += __shfl_xor(a.x, mask);
  a.y += __shfl_xor(a.y, mask);
  a.z += __shfl_xor(a.z, mask);
  a.w += __shfl_xor(a.w, mask);
}

// ---------------- layer-0 fused gather (sorted output rows) ----------------
__global__ __launch_bounds__(256) void gather_l0_kernel(
    const int* __restrict__ order,
    const int* __restrict__ rsP, const uint4* __restrict__ recP,
    const int* __restrict__ rsB, const uint4* __restrict__ recB,
    const unsigned short* __restrict__ Y0a, const unsigned short* __restrict__ Y0b,
    const float* __restrict__ feats4, const float* __restrict__ Wd0, const float* __restrict__ bd0,
    const float* __restrict__ b0a, const float* __restrict__ b0b,
    float* __restrict__ hf, unsigned short* __restrict__ hb) {
  const int sw = swz_block(blockIdx.x, gridDim.x);
  const int p4 = sw*4 + (threadIdx.x >> 6);   // sorted position
  const int node = order[p4];                  // original node (CSR + feats)
  const int lane = threadIdx.x & 63;
  const int j = lane >> 3, cg = lane & 7;
  const int koff = ((j&4)<<2) | ((j&2)<<1) | (j&1);
  f32x4 accP = {0.f,0.f,0.f,0.f}, accB = {0.f,0.f,0.f,0.f};
  {
    int e0 = rsP[node], e1 = rsP[node+1];
    int e = e0;
    for (; e + 4 <= e1; e += 4) {
      uint4 r[4]; uint2 y[4];
#pragma unroll
      for (int i=0;i<4;i++) r[i] = recP[e+i];
#pragma unroll
      for (int i=0;i<4;i++) y[i] = *(const uint2*)(Y0a + ((size_t)(r[i].x + koff))*32 + cg*4);
#pragma unroll
      for (int i=0;i<4;i++) {
        float w = corner_w(r[i], j);
        accP.x += w*bfl(y[i].x); accP.y += w*bfh(y[i].x);
        accP.z += w*bfl(y[i].y); accP.w += w*bfh(y[i].y);
      }
    }
    for (; e < e1; e++) {
      uint4 r = recP[e];
      uint2 y = *(const uint2*)(Y0a + ((size_t)(r.x + koff))*32 + cg*4);
      float w = corner_w(r, j);
      accP.x += w*bfl(y.x); accP.y += w*bfh(y.x);
      accP.z += w*bfl(y.y); accP.w += w*bfh(y.y);
    }
  }
  {
    int e0 = rsB[node], e1 = rsB[node+1];
    int e = e0;
    for (; e + 4 <= e1; e += 4) {
      uint4 r[4]; uint2 y[4];
#pragma unroll
      for (int i=0;i<4;i++) r[i] = recB[e+i];
#pragma unroll
      for (int i=0;i<4;i++) y[i] = *(const uint2*)(Y0b + ((size_t)(r[i].x + koff))*32 + cg*4);
#pragma unroll
      for (int i=0;i<4;i++) {
        float w = corner_w(r[i], j);
        accB.x += w*bfl(y[i].x); accB.y += w*bfh(y[i].x);
        accB.z += w*bfl(y[i].y); accB.w += w*bfh(y[i].y);
      }
    }
    for (; e < e1; e++) {
      uint4 r = recB[e];
      uint2 y = *(const uint2*)(Y0b + ((size_t)(r.x + koff))*32 + cg*4);
      float w = corner_w(r, j);
      accB.x += w*bfl(y.x); accB.y += w*bfh(y.x);
      accB.z += w*bfl(y.y); accB.w += w*bfh(y.y);
    }
  }
  xor_add4(accP, 8);  xor_add4(accP, 16); xor_add4(accP, 32);
  xor_add4(accB, 8);  xor_add4(accB, 16); xor_add4(accB, 32);
  if (lane < 8) {
    float4 f = *(const float4*)(feats4 + (size_t)node*4);
    float4 ba = *(const float4*)(b0a + cg*4);
    float4 bb = *(const float4*)(b0b + cg*4);
    float4 bdv = *(const float4*)(bd0 + cg*4);
    float4 w0v = *(const float4*)(Wd0 + 0*32 + cg*4);
    float4 w1v = *(const float4*)(Wd0 + 1*32 + cg*4);
    float4 w2v = *(const float4*)(Wd0 + 2*32 + cg*4);
    float4 w3v = *(const float4*)(Wd0 + 3*32 + cg*4);
    float4 dd;
    dd.x = bdv.x + f.x*w0v.x + f.y*w1v.x + f.z*w2v.x + f.w*w3v.x;
    dd.y = bdv.y + f.x*w0v.y + f.y*w1v.y + f.z*w2v.y + f.w*w3v.y;
    dd.z = bdv.z + f.x*w0v.z + f.y*w1v.z + f.z*w2v.z + f.w*w3v.z;
    dd.w = bdv.w + f.x*w0v.w + f.y*w1v.w + f.z*w2v.w + f.w*w3v.w;
    float4 c0; c0.x = accP.x + ba.x; c0.y = accP.y + ba.y; c0.z = accP.z + ba.z; c0.w = accP.w + ba.w;
    float4 cb; cb.x = accB.x + bb.x; cb.y = accB.y + bb.y; cb.z = accB.z + bb.z; cb.w = accB.w + bb.w;
    size_t o = (size_t)p4*96;
    *(float4*)(hf + o + cg*4)      = c0;
    *(float4*)(hf + o + 32 + cg*4) = cb;
    *(float4*)(hf + o + 64 + cg*4) = dd;
    ushort4 u0 = {f2bf(c0.x), f2bf(c0.y), f2bf(c0.z), f2bf(c0.w)};
    ushort4 u1 = {f2bf(cb.x), f2bf(cb.y), f2bf(cb.z), f2bf(cb.w)};
    ushort4 u2 = {f2bf(dd.x), f2bf(dd.y), f2bf(dd.z), f2bf(dd.w)};
    *(ushort4*)(hb + o + cg*4)      = u0;
    *(ushort4*)(hb + o + 32 + cg*4) = u1;
    *(ushort4*)(hb + o + 64 + cg*4) = u2;
  }
}

// ---------------- fused conv-gather + dense, d=64 (sorted layout) ----------------
template<int DCIN, bool ADDSKIP>
__global__ __launch_bounds__(128) void gather64_kernel(
    const int* __restrict__ order,
    const int* __restrict__ rs, const uint4* __restrict__ rec,
    const unsigned short* __restrict__ Y,
    const float* __restrict__ Xf, const float* __restrict__ Wd, const float* __restrict__ bd,
    const float* __restrict__ bconv, const float* __restrict__ skip,
    float* __restrict__ outf, unsigned short* __restrict__ outb) {
  const int p = swz_block(blockIdx.x, gridDim.x);  // sorted position
  const int node = order[p];                        // original node (CSR only)
  const int wave = threadIdx.x >> 6;
  const int lane = threadIdx.x & 63;
  const int j = lane >> 3, cg = lane & 7;
  const int koff = ((j&4)<<2) | ((j&2)<<1) | (j&1);
  __shared__ __align__(16) float red[64*16];
  f32x4 accA = {0.f,0.f,0.f,0.f}, accB = {0.f,0.f,0.f,0.f};
  const int e0 = rs[node], e1 = rs[node+1];
  int e = e0 + wave;
  for (; e + 6 < e1; e += 8) {           // edges e, e+2, e+4, e+6
    uint4 r[4]; uint4 y[4];
#pragma unroll
    for (int i=0;i<4;i++) r[i] = rec[e + i*2];
#pragma unroll
    for (int i=0;i<4;i++) y[i] = *(const uint4*)(Y + ((size_t)(r[i].x + koff))*64 + cg*8);
#pragma unroll
    for (int i=0;i<4;i++) {
      float w = corner_w(r[i], j);
      accA.x += w*bfl(y[i].x); accA.y += w*bfh(y[i].x);
      accA.z += w*bfl(y[i].y); accA.w += w*bfh(y[i].y);
      accB.x += w*bfl(y[i].z); accB.y += w*bfh(y[i].z);
      accB.z += w*bfl(y[i].w); accB.w += w*bfh(y[i].w);
    }
  }
  for (; e < e1; e += 2) {
    uint4 r = rec[e];
    uint4 y = *(const uint4*)(Y + ((size_t)(r.x + koff))*64 + cg*8);
    float w = corner_w(r, j);
    accA.x += w*bfl(y.x); accA.y += w*bfh(y.x);
    accA.z += w*bfl(y.y); accA.w += w*bfh(y.y);
    accB.x += w*bfl(y.z); accB.y += w*bfh(y.z);
    accB.z += w*bfl(y.w); accB.w += w*bfh(y.w);
  }
  // dense branch: k-split across 128 threads (16 segments of DCIN/16), Xf sorted
  constexpr int KQ = DCIN/16;
  f32x4 ddA = {0.f,0.f,0.f,0.f}, ddB = {0.f,0.f,0.f,0.f};
  {
    const int seg = wave*8 + j;
    const float* x = Xf + (size_t)p*DCIN + seg*KQ;
#pragma unroll
    for (int kk=0; kk<KQ; kk++) {
      float xv = x[kk];
      float4 w0 = *(const float4*)(Wd + (size_t)(seg*KQ+kk)*64 + cg*8);
      float4 w1 = *(const float4*)(Wd + (size_t)(seg*KQ+kk)*64 + cg*8 + 4);
      ddA.x += xv*w0.x; ddA.y += xv*w0.y; ddA.z += xv*w0.z; ddA.w += xv*w0.w;
      ddB.x += xv*w1.x; ddB.y += xv*w1.y; ddB.z += xv*w1.z; ddB.w += xv*w1.w;
    }
  }
  if (wave == 1) {
    *(f32x4*)(red + lane*16)      = accA;
    *(f32x4*)(red + lane*16 + 4)  = accB;
    *(f32x4*)(red + lane*16 + 8)  = ddA;
    *(f32x4*)(red + lane*16 + 12) = ddB;
  }
  __syncthreads();
  if (wave == 0) {
    {
      f32x4 oA = *(const f32x4*)(red + lane*16);
      f32x4 oB = *(const f32x4*)(red + lane*16 + 4);
      f32x4 oC = *(const f32x4*)(red + lane*16 + 8);
      f32x4 oD = *(const f32x4*)(red + lane*16 + 12);
      accA.x += oA.x; accA.y += oA.y; accA.z += oA.z; accA.w += oA.w;
      accB.x += oB.x; accB.y += oB.y; accB.z += oB.z; accB.w += oB.w;
      ddA.x += oC.x; ddA.y += oC.y; ddA.z += oC.z; ddA.w += oC.w;
      ddB.x += oD.x; ddB.y += oD.y; ddB.z += oD.z; ddB.w += oD.w;
    }
    xor_add4(accA, 8); xor_add4(accA, 16); xor_add4(accA, 32);
    xor_add4(accB, 8); xor_add4(accB, 16); xor_add4(accB, 32);
    xor_add4(ddA, 8);  xor_add4(ddA, 16);  xor_add4(ddA, 32);
    xor_add4(ddB, 8);  xor_add4(ddB, 16);  xor_add4(ddB, 32);
    if (lane < 8) {   // j == 0: cg = lane, channels cg*8 .. cg*8+7
      float4 bc0 = *(const float4*)(bconv + cg*8);
      float4 bc1 = *(const float4*)(bconv + cg*8 + 4);
      float4 bd0v = *(const float4*)(bd + cg*8);
      float4 bd1v = *(const float4*)(bd + cg*8 + 4);
      float4 v0, v1;
      v0.x = fmaxf(accA.x + bc0.x, 0.f) + fmaxf(ddA.x + bd0v.x, 0.f);
      v0.y = fmaxf(accA.y + bc0.y, 0.f) + fmaxf(ddA.y + bd0v.y, 0.f);
      v0.z = fmaxf(accA.z + bc0.z, 0.f) + fmaxf(ddA.z + bd0v.z, 0.f);
      v0.w = fmaxf(accA.w + bc0.w, 0.f) + fmaxf(ddA.w + bd0v.w, 0.f);
      v1.x = fmaxf(accB.x + bc1.x, 0.f) + fmaxf(ddB.x + bd1v.x, 0.f);
      v1.y = fmaxf(accB.y + bc1.y, 0.f) + fmaxf(ddB.y + bd1v.y, 0.f);
      v1.z = fmaxf(accB.z + bc1.z, 0.f) + fmaxf(ddB.z + bd1v.z, 0.f);
      v1.w = fmaxf(accB.w + bc1.w, 0.f) + fmaxf(ddB.w + bd1v.w, 0.f);
      if (ADDSKIP) {
        float4 s0 = *(const float4*)(skip + (size_t)p*64 + cg*8);
        float4 s1 = *(const float4*)(skip + (size_t)p*64 + cg*8 + 4);
        v0.x += s0.x; v0.y += s0.y; v0.z += s0.z; v0.w += s0.w;
        v1.x += s1.x; v1.y += s1.y; v1.z += s1.z; v1.w += s1.w;
      }
      *(float4*)(outf + (size_t)p*64 + cg*8)     = v0;
      *(float4*)(outf + (size_t)p*64 + cg*8 + 4) = v1;
      ushort4 u0 = {f2bf(v0.x), f2bf(v0.y), f2bf(v0.z), f2bf(v0.w)};
      ushort4 u1 = {f2bf(v1.x), f2bf(v1.y), f2bf(v1.z), f2bf(v1.w)};
      *(ushort4*)(outb + (size_t)p*64 + cg*8)     = u0;
      *(ushort4*)(outb + (size_t)p*64 + cg*8 + 4) = u1;
    }
  }
}

// ---------------- layer-3 gather (d=3), sorted layout in, original out ----------------
__global__ __launch_bounds__(256) void gather3_kernel(
    const int* __restrict__ order,
    const int* __restrict__ rs, const uint4* __restrict__ rec,
    const unsigned short* __restrict__ Y3,
    const float* __restrict__ h2f, const float* __restrict__ Wd3, const float* __restrict__ bd3,
    const float* __restrict__ b3, float* __restrict__ out) {
  const int sw = swz_block(blockIdx.x, gridDim.x);
  const int p4 = sw*4 + (threadIdx.x >> 6);
  const int node = order[p4];
  const int lane = threadIdx.x & 63;
  const int e2 = lane >> 5, j = (lane >> 2) & 7, dd = lane & 3;
  const int koff = ((j&4)<<2)|((j&2)<<1)|(j&1);
  float acc = 0.f;
  const int e0 = rs[node], e1 = rs[node+1];
  for (int e = e0; e < e1; e += 2) {
    int ee = e + e2;
    bool v = ee < e1;
    int ix = v ? ee : e;
    uint4 r = rec[ix];
    float w = v ? corner_w(r, j) : 0.f;
    acc += w * bf2f(Y3[((size_t)(r.x + koff))*4 + dd]);
  }
  acc += __shfl_xor(acc, 4);
  acc += __shfl_xor(acc, 8);
  acc += __shfl_xor(acc, 16);
  acc += __shfl_down(acc, 32);
  if (lane < 3) {
    float d3 = bd3[lane];
    const float* x = h2f + (size_t)p4*64;
#pragma unroll 8
    for (int c=0;c<64;c++) d3 += x[c]*Wd3[c*3 + lane];
    out[(size_t)node*3 + lane] = acc + b3[lane] + d3;
  }
}

extern "C" void kernel_launch(void* const* d_in, const int* in_sizes, int n_in,
                              void* d_out, int out_size, void* d_ws, size_t ws_size,
                              hipStream_t stream) {
  const float* pos    = (const float*)d_in[0];
  const float* vel    = (const float*)d_in[1];
  const float* mass   = (const float*)d_in[2];
  const float* bh_pos = (const float*)d_in[3];
  const float* bh_vel = (const float*)d_in[4];
  const float* bh_mass= (const float*)d_in[5];
  const int* pp_src   = (const int*)d_in[6];
  const int* pp_dst   = (const int*)d_in[7];
  const int* bh_src   = (const int*)d_in[8];
  const int* bh_dst   = (const int*)d_in[9];
  const float* W0a=(const float*)d_in[10]; const float* b0a=(const float*)d_in[11];
  const float* Wd0=(const float*)d_in[12]; const float* bd0=(const float*)d_in[13];
  const float* W0b=(const float*)d_in[14]; const float* b0b=(const float*)d_in[15];
  const float* W1 =(const float*)d_in[16]; const float* b1 =(const float*)d_in[17];
  const float* Wd1=(const float*)d_in[18]; const float* bd1=(const float*)d_in[19];
  const float* W2 =(const float*)d_in[20]; const float* b2 =(const float*)d_in[21];
  const float* Wd2=(const float*)d_in[22]; const float* bd2=(const float*)d_in[23];
  const float* W3 =(const float*)d_in[24]; const float* b3 =(const float*)d_in[25];
  const float* Wd3=(const float*)d_in[26]; const float* bd3=(const float*)d_in[27];
  float* out = (float*)d_out;
  char* wsb = (char*)d_ws;

  size_t off = 0;
  auto alloc = [&](size_t nbytes){ size_t o = off; off += (nbytes + 255) & ~((size_t)255); return o; };
  size_t feats_o   = alloc((size_t)NPART*4*4);
  size_t bhfeats_o = alloc((size_t)NBHX*4*4);
  size_t rs_pp_o   = alloc(8256*4);
  size_t rs_bh_o   = alloc(8256*4);
  size_t rec_pp_o  = alloc((size_t)EPX*16);
  size_t rec_bh_o  = alloc((size_t)EBX*16);
  size_t hf_o  = alloc((size_t)NPART*96*4);
  size_t hb_o  = alloc((size_t)NPART*96*2);
  size_t h1f_o = alloc((size_t)NPART*64*4);
  size_t h1b_o = alloc((size_t)NPART*64*2);
  size_t h2f_o = alloc((size_t)NPART*64*4);
  size_t h2b_o = alloc((size_t)NPART*64*2);
  size_t bt1_o = alloc((size_t)4096*96*2);
  size_t bt2_o = alloc((size_t)4096*64*2);
  size_t bt3_o = alloc((size_t)256*64*2);
  size_t y0b_o = alloc((size_t)NBHX*64*32*2);
  size_t cell_o = alloc((size_t)NPART*4);
  size_t hist_o = alloc((size_t)4096*4);
  size_t order_o= alloc((size_t)NPART*4);
  size_t inv_o  = alloc((size_t)NPART*4);
  size_t y_o   = alloc((size_t)NPART*4096*2);   // shared: Y0a / Y1 / Y2 / Y3

  float* featsP = (float*)(wsb + feats_o); float* bhfeatsP = (float*)(wsb + bhfeats_o);
  int* rsPP = (int*)(wsb + rs_pp_o); int* rsBH = (int*)(wsb + rs_bh_o);
  uint4* recP = (uint4*)(wsb + rec_pp_o);
  uint4* recB = (uint4*)(wsb + rec_bh_o);
  float* hf  = (float*)(wsb + hf_o);  unsigned short* hb  = (unsigned short*)(wsb + hb_o);
  float* h1f = (float*)(wsb + h1f_o); unsigned short* h1b = (unsigned short*)(wsb + h1b_o);
  float* h2f = (float*)(wsb + h2f_o); unsigned short* h2b = (unsigned short*)(wsb + h2b_o);
  unsigned short* BT1 = (unsigned short*)(wsb + bt1_o);
  unsigned short* BT2 = (unsigned short*)(wsb + bt2_o);
  unsigned short* BT3 = (unsigned short*)(wsb + bt3_o);
  unsigned short* Y0b = (unsigned short*)(wsb + y0b_o);
  int* cellA = (int*)(wsb + cell_o);
  int* histA = (int*)(wsb + hist_o);
  int* orderA= (int*)(wsb + order_o);
  int* invA  = (int*)(wsb + inv_o);
  unsigned short* Ybuf = (unsigned short*)(wsb + y_o);

  // ---- prep ----
  prep_kernel<<<(2*(NPART+1)+255)/256, 256, 0, stream>>>(vel, mass, bh_vel, bh_mass,
                                                         featsP, bhfeatsP, pp_dst, bh_dst,
                                                         rsPP, rsBH, histA);
  cellw_kernel<<<32 + (4096*96 + 4096*64 + 256*64 + 255)/256, 256, 0, stream>>>(
      pos, cellA, histA, W1, W2, W3, BT1, BT2, BT3);
  scan_kernel<<<1, 256, 0, stream>>>(histA, histA);
  scatterorder_kernel<<<NPART/256, 256, 0, stream>>>(cellA, histA, orderA, invA);
  geom2_kernel<<<(EPX+EBX+255)/256, 256, 0, stream>>>(pos, bh_pos, pp_src, pp_dst, bh_src, bh_dst,
                                                      invA, recP, recB);

  // ---- layer 0 ----
  y0_kernel<<<((NPART+NBHX)*256+255)/256, 256, 0, stream>>>(orderA, featsP, bhfeatsP, W0a, W0b, Ybuf, Y0b);
  gather_l0_kernel<<<NPART/4, 256, 0, stream>>>(orderA, rsPP, recP, rsBH, recB,
                                                Ybuf, Y0b, featsP, Wd0, bd0, b0a, b0b, hf, hb);
  // ---- layer 1 ----
  {
    dim3 g(NPART/128, 4096/64);
    gemm_y_kernel<<<g, 256, 0, stream>>>(hb, BT1, 96, 4096, Ybuf);
    gather64_kernel<96,false><<<NPART, 128, 0, stream>>>(orderA, rsPP, recP, Ybuf,
        hf, Wd1, bd1, b1, nullptr, h1f, h1b);
  }
  // ---- layer 2 ----
  {
    dim3 g(NPART/128, 4096/64);
    gemm_y_kernel<<<g, 256, 0, stream>>>(h1b, BT2, 64, 4096, Ybuf);
    gather64_kernel<64,true><<<NPART, 128, 0, stream>>>(orderA, rsPP, recP, Ybuf,
        h1f, Wd2, bd2, b2, h1f, h2f, h2b);
  }
  // ---- layer 3 ----
  {
    dim3 g(NPART/128, 256/64);
    gemm_y_kernel<<<g, 256, 0, stream>>>(h2b, BT3, 64, 256, Ybuf);
    gather3_kernel<<<NPART/4, 256, 0, stream>>>(orderA, rsPP, recP, Ybuf,
        h2f, Wd3, bd3, b3, out);
  }
}